// Round 6
// baseline (369.809 us; speedup 1.0000x reference)
//
#include <hip/hip_runtime.h>
#include <math.h>

// MHA forward: B=4, S=2048, E=1024, H=16, D=64. bf16 MFMA path.
// Round 10:
//  (A) gemm_qkv: two M-tiles per block (bm tiles x and x+32 share a block,
//      same bn0 -> weight tile stays hot in L2). Grid 32x8x3 = 768 blocks =
//      exactly 3/CU (capacity 4 at VGPR~112 / 32KB LDS) -> single-phase
//      residency, no half-empty 2-blocks/CU tail phase (was 6/CU demand
//      over 4/CU capacity -> 4+2 phases; phase 2 = 1 wave/SIMD, rate
//      collapse).
//  (B) attn_fwd: s_setprio(1) around the QK^T and PV MFMA clusters (T5 —
//      effective for phase-diverse waves, m191).
// Everything else unchanged from round 9.

#define EMBED 1024
#define SEQ   2048
#define NH    16
#define HD    64
#define QSCALE 0.18033688011112042f   // 0.125 * log2(e), folded into Q proj

typedef __attribute__((ext_vector_type(4))) float f32x4;
typedef __attribute__((ext_vector_type(8))) short s16x8;
typedef __attribute__((ext_vector_type(4))) short s16x4;
typedef __attribute__((ext_vector_type(4))) unsigned int u32x4;
typedef __attribute__((ext_vector_type(2))) unsigned int u32x2;

#define GLDS16(gp, lp) __builtin_amdgcn_global_load_lds( \
    (const __attribute__((address_space(1))) void*)(gp), \
    (__attribute__((address_space(3))) void*)(lp), 16, 0, 0)

__device__ __forceinline__ unsigned short f2bf(float f) {   // RNE
    unsigned int u = __builtin_bit_cast(unsigned int, f);
    u += 0x7fffu + ((u >> 16) & 1u);
    return (unsigned short)(u >> 16);
}
// pack two fp32 -> bf16x2 dword by truncation (1 v_perm_b32)
__device__ __forceinline__ unsigned int pkbf(float lo, float hi) {
    return __builtin_amdgcn_perm(__builtin_bit_cast(unsigned int, hi),
                                 __builtin_bit_cast(unsigned int, lo),
                                 0x07060302u);
}

// ---------- fp32 -> bf16 (RNE): 4 weight tensors + 3 activation tensors ----
struct CvtArgs { const float* s[7]; unsigned short* d[7]; int n4[7]; };
__global__ void cvt_all(CvtArgs ca)
{
    const int t = blockIdx.y;
    const float* in = ca.s[t];
    unsigned short* out = ca.d[t];
    const int n4 = ca.n4[t];
    const int stride = gridDim.x * 256;
    for (int i = blockIdx.x * 256 + threadIdx.x; i < n4; i += stride) {
        f32x4 v = *(const f32x4*)(in + (size_t)i * 4);
        s16x4 p;
        p[0] = (short)f2bf(v[0]); p[1] = (short)f2bf(v[1]);
        p[2] = (short)f2bf(v[2]); p[3] = (short)f2bf(v[3]);
        *(s16x4*)(out + (size_t)i * 4) = p;
    }
}

// ---------------- QKV projection (z = 0:Q, 1:K, 2:V), pure bf16 ------------
// Two M-tiles per block: bm tiles blockIdx.x and blockIdx.x+32.
struct ProjArgs {
    const unsigned short* X[3];
    const unsigned short* W[3];
    const float* Bz[3];
    unsigned short* Oz[3];
};
__global__ void __launch_bounds__(256)
gemm_qkv(ProjArgs pa)
{
    __shared__ unsigned short Ab[128 * 64];    // bf16 X tile (16 KB), swizzled
    __shared__ unsigned short Bb[128 * 64];    // bf16 W tile (16 KB), swizzled
    const int z = blockIdx.z;
    const unsigned short* Xb = pa.X[z];
    const unsigned short* Wb = pa.W[z];
    const float* bias = pa.Bz[z];
    unsigned short* Out = pa.Oz[z];
    const float scale = (z == 0) ? QSCALE : 1.0f;
    const int tid = threadIdx.x, lane = tid & 63, wv = tid >> 6;
    const int g = lane >> 4, c = lane & 15;
    const int wx = wv & 1, wy = wv >> 1;
    const int bn0 = blockIdx.y * 128;

    for (int half = 0; half < 2; ++half) {
        const int bm0 = (blockIdx.x + half * 32) * 128;

        f32x4 acc[4][4];
#pragma unroll
        for (int i = 0; i < 4; ++i)
#pragma unroll
            for (int n = 0; n < 4; ++n) acc[i][n] = f32x4{0.f, 0.f, 0.f, 0.f};

        for (int k0 = 0; k0 < EMBED; k0 += 64) {
            __syncthreads();
#pragma unroll
            for (int cc = 0; cc < 4; ++cc) {   // A bf16: 8 chunks/row, swz ^(row&7)
                int li = cc * 256 + tid;
                int row = li >> 3, ch = (li & 7) ^ (row & 7);
                GLDS16(Xb + (size_t)(bm0 + row) * EMBED + k0 + ch * 8,
                       Ab + cc * 2048 + wv * 512);
            }
#pragma unroll
            for (int cc = 0; cc < 4; ++cc) {   // B bf16: 8 chunks/row, swz ^(row&7)
                int li = cc * 256 + tid;
                int row = li >> 3, ch = (li & 7) ^ (row & 7);
                GLDS16(Wb + (size_t)(bn0 + row) * EMBED + k0 + ch * 8,
                       Bb + cc * 2048 + wv * 512);
            }
            __syncthreads();
#pragma unroll
            for (int ks = 0; ks < 2; ++ks) {
                const int ib = ((ks * 4 + g) ^ (c & 7)) * 8;
                s16x8 af[4], bfr[4];
#pragma unroll
                for (int i = 0; i < 4; ++i)
                    af[i] = *(const s16x8*)(&Ab[(wy * 64 + i * 16 + c) * 64 + ib]);
#pragma unroll
                for (int n = 0; n < 4; ++n)
                    bfr[n] = *(const s16x8*)(&Bb[(wx * 64 + n * 16 + c) * 64 + ib]);
#pragma unroll
                for (int i = 0; i < 4; ++i)
#pragma unroll
                    for (int n = 0; n < 4; ++n)
                        acc[i][n] = __builtin_amdgcn_mfma_f32_16x16x32_bf16(af[i], bfr[n], acc[i][n], 0, 0, 0);
            }
        }
        if (z < 2) {        // Q/K -> [B][H][S][D]
#pragma unroll
            for (int i = 0; i < 4; ++i) {
                int m0 = bm0 + wy * 64 + i * 16 + g * 4;
                int bb = m0 >> 11, s0 = m0 & 2047;
#pragma unroll
                for (int n = 0; n < 4; ++n) {
                    int ncol = bn0 + wx * 64 + n * 16 + c;
                    float bv = bias[ncol];
                    int hh = ncol >> 6, dd = ncol & 63;
                    size_t base = (((size_t)bb * NH + hh) * SEQ + s0) * HD + dd;
#pragma unroll
                    for (int r = 0; r < 4; ++r)
                        Out[base + (size_t)r * HD] = f2bf((acc[i][n][r] + bv) * scale);
                }
            }
        } else {            // V -> V^T [B][H][D][S], 8B stores
#pragma unroll
            for (int i = 0; i < 4; ++i) {
                int m0 = bm0 + wy * 64 + i * 16 + g * 4;
                int bb = m0 >> 11, s0 = m0 & 2047;
#pragma unroll
                for (int n = 0; n < 4; ++n) {
                    int ncol = bn0 + wx * 64 + n * 16 + c;
                    float bv = bias[ncol];
                    int hh = ncol >> 6, dd = ncol & 63;
                    s16x4 pk;
#pragma unroll
                    for (int r = 0; r < 4; ++r) pk[r] = (short)f2bf(acc[i][n][r] + bv);
                    *(s16x4*)(&Out[(((size_t)bb * NH + hh) * HD + dd) * SEQ + s0]) = pk;
                }
            }
        }
    }
}

// ---------------- output projection -----------------------------------------
__global__ void __launch_bounds__(256)
gemm_out(const unsigned short* __restrict__ Xb, const unsigned short* __restrict__ Wb,
         const float* __restrict__ bias, float* __restrict__ Out)
{
    __shared__ unsigned short Ab[128 * 64];
    __shared__ unsigned short Bb[128 * 64];
    const int tid = threadIdx.x;
    const int lane = tid & 63, wv = tid >> 6;
    const int g = lane >> 4, c = lane & 15;
    const int wx = wv & 1, wy = wv >> 1;
    const int bm0 = blockIdx.x * 128, bn0 = blockIdx.y * 128;

    f32x4 acc[4][4];
#pragma unroll
    for (int i = 0; i < 4; ++i)
#pragma unroll
        for (int n = 0; n < 4; ++n) acc[i][n] = f32x4{0.f, 0.f, 0.f, 0.f};

    for (int k0 = 0; k0 < EMBED; k0 += 64) {
        __syncthreads();
#pragma unroll
        for (int cc = 0; cc < 4; ++cc) {
            int li = cc * 256 + tid;
            int row = li >> 3, ch = (li & 7) ^ (row & 7);
            GLDS16(Xb + (size_t)(bm0 + row) * EMBED + k0 + ch * 8,
                   Ab + cc * 2048 + wv * 512);
        }
#pragma unroll
        for (int cc = 0; cc < 4; ++cc) {
            int li = cc * 256 + tid;
            int row = li >> 3, ch = (li & 7) ^ (row & 7);
            GLDS16(Wb + (size_t)(bn0 + row) * EMBED + k0 + ch * 8,
                   Bb + cc * 2048 + wv * 512);
        }
        __syncthreads();
#pragma unroll
        for (int ks = 0; ks < 2; ++ks) {
            const int ib = ((ks * 4 + g) ^ (c & 7)) * 8;
            s16x8 af[4], bfr[4];
#pragma unroll
            for (int i = 0; i < 4; ++i)
                af[i] = *(const s16x8*)(&Ab[(wy * 64 + i * 16 + c) * 64 + ib]);
#pragma unroll
            for (int n = 0; n < 4; ++n)
                bfr[n] = *(const s16x8*)(&Bb[(wx * 64 + n * 16 + c) * 64 + ib]);
#pragma unroll
            for (int i = 0; i < 4; ++i)
#pragma unroll
                for (int n = 0; n < 4; ++n)
                    acc[i][n] = __builtin_amdgcn_mfma_f32_16x16x32_bf16(af[i], bfr[n], acc[i][n], 0, 0, 0);
        }
    }
#pragma unroll
    for (int i = 0; i < 4; ++i) {
#pragma unroll
        for (int n = 0; n < 4; ++n) {
            int ncol = bn0 + wx * 64 + n * 16 + c;
            float bv = bias[ncol];
#pragma unroll
            for (int r = 0; r < 4; ++r) {
                int m = bm0 + wy * 64 + i * 16 + g * 4 + r;
                Out[(size_t)m * EMBED + ncol] = acc[i][n][r] + bv;
            }
        }
    }
}

// ---------------- causal flash attention (8-wave, unpaired stripes) ---------
// grid (NH, B, 16); block = 8 waves (512 thr). One stripe per block: waves
// 0-3 own q-tile 2jj, waves 4-7 own q-tile 2jj+1, sharing one double-buffered
// K/V LDS pipeline. jj = 15 - blockIdx.z puts the 34-iter stripes first in
// dispatch order (global LPT); LDS 51200 -> 3 blocks/CU co-resident.
// defer-max: O-rescale skipped unless tile max exceeds m_run+8 (exp2 dom).
// setprio(1) around QK^T and PV MFMA clusters (T5).
__global__ void __launch_bounds__(512, 4)
attn_fwd(const unsigned short* __restrict__ Qb, const unsigned short* __restrict__ Kb,
         const unsigned short* __restrict__ Vg, unsigned short* __restrict__ Ob)
{
    __shared__ unsigned short Kt[2][64 * 64];  // K tile [s][d], swizzled (16 KB)
    __shared__ unsigned short Vt[2][64 * 64];  // V^T tile [d][s], swizzled (16 KB)
    __shared__ unsigned int   Pb[8][16 * 36];  // per-wave P, dwords, stride 36
    const int tid = threadIdx.x, lane = tid & 63, wv = tid >> 6;
    const int g = lane >> 4, c = lane & 15;
    const int wq = wv >> 2, wr = wv & 3;       // q-tile select / row-group
    const int h = blockIdx.x, b = blockIdx.y;
    const int jj = 15 - blockIdx.z;            // stripe (LPT: big first)
    const size_t bh = (size_t)b * NH + h;
    const unsigned short* K0 = Kb + bh * SEQ * HD;
    const unsigned short* V0 = Vg + bh * HD * SEQ;
    unsigned int* Pw = &Pb[wv][0];
    const int x0 = (g ^ (c & 7)) * 8;          // swizzled chunk offsets (LDS)
    const int x1 = ((4 + g) ^ (c & 7)) * 8;
    // staging: 512 threads cover 64 rows x 8 chunks (one GLDS16 each)
    const int srow = tid >> 3, sch = (tid & 7) ^ (srow & 7);
    const int kr = srow * HD + sch * 8;
    const int vr = srow * SEQ + sch * 8;

    const int qt = 2 * jj + wq;          // this wave's q-tile
    const int kmax = 2 * jj + 1;         // block-wide last k-tile
    const unsigned short* Qp = Qb + (bh * SEQ + qt * 64 + wr * 16) * HD;
    s16x8 qf0 = *(const s16x8*)(Qp + c * HD + g * 8);
    s16x8 qf1 = *(const s16x8*)(Qp + c * HD + 32 + g * 8);
    f32x4 o[4];
#pragma unroll
    for (int dt = 0; dt < 4; ++dt) o[dt] = f32x4{0.f, 0.f, 0.f, 0.f};
    float m_run = -INFINITY, l_run = 0.f;

    {   // prologue: stage K/V(0) into buffer 0
        GLDS16(K0 + kr, &Kt[0][0] + wv * 512);
        GLDS16(V0 + vr, &Vt[0][0] + wv * 512);
    }

    for (int kt = 0; kt <= kmax; ++kt) {
        __syncthreads();           // publishes buffer kt&1 (drains GLDS)
        const int cur = kt & 1;
        if (kt < kmax) {           // prefetch kt+1 into the other buffer
            GLDS16(K0 + (size_t)(kt + 1) * 64 * HD + kr, &Kt[cur ^ 1][0] + wv * 512);
            GLDS16(V0 + (kt + 1) * 64 + vr, &Vt[cur ^ 1][0] + wv * 512);
        }
        if (kt > qt) continue;     // wave-uniform: lower q-tile idles last iter
        const unsigned short* Kc = &Kt[cur][0];
        const unsigned short* Vc = &Vt[cur][0];

        const int ntmax = (kt == qt) ? wr : 3;   // skip fully-masked k-subtiles
        f32x4 sc[4];
        __builtin_amdgcn_s_setprio(1);
#pragma unroll
        for (int nt = 0; nt < 4; ++nt) {
            if (nt <= ntmax) {
                f32x4 a = f32x4{0.f, 0.f, 0.f, 0.f};
                s16x8 kf0 = *(const s16x8*)(&Kc[(nt * 16 + c) * 64 + x0]);
                s16x8 kf1 = *(const s16x8*)(&Kc[(nt * 16 + c) * 64 + x1]);
                a = __builtin_amdgcn_mfma_f32_16x16x32_bf16(kf0, qf0, a, 0, 0, 0);
                a = __builtin_amdgcn_mfma_f32_16x16x32_bf16(kf1, qf1, a, 0, 0, 0);
                sc[nt] = a;
            } else {
                sc[nt] = f32x4{-INFINITY, -INFINITY, -INFINITY, -INFINITY};
            }
        }
        __builtin_amdgcn_s_setprio(0);
        if (kt == qt) {   // diagonal tile: mask k > q
#pragma unroll
            for (int nt = 0; nt < 4; ++nt)
#pragma unroll
                for (int r = 0; r < 4; ++r)
                    if (nt * 16 + g * 4 + r > wr * 16 + c) sc[nt][r] = -INFINITY;
        }
        // online softmax: lane owns q-column c; k spread over regs+g
        float mloc = -INFINITY;
#pragma unroll
        for (int nt = 0; nt < 4; ++nt)
            mloc = fmaxf(mloc, fmaxf(fmaxf(sc[nt][0], sc[nt][1]),
                                     fmaxf(sc[nt][2], sc[nt][3])));
        mloc = fmaxf(mloc, __shfl_xor(mloc, 16));
        mloc = fmaxf(mloc, __shfl_xor(mloc, 32));
        // defer-max (T13): rescale only when growth exceeds 8 (exp2 domain);
        // P bounded by 2^8 = 256, safe in bf16 pack + fp32 accum.
        if (__any(mloc > m_run + 8.0f)) {
            float mnew = fmaxf(m_run, mloc);
            float alpha = __builtin_amdgcn_exp2f(m_run - mnew);
            m_run = mnew;
            l_run *= alpha;
            float av[4];
#pragma unroll
            for (int r = 0; r < 4; ++r) av[r] = __shfl(alpha, g * 4 + r, 16);
#pragma unroll
            for (int dt = 0; dt < 4; ++dt)
#pragma unroll
                for (int r = 0; r < 4; ++r) o[dt][r] *= av[r];
        }
        float rs = 0.f;
#pragma unroll
        for (int nt = 0; nt < 4; ++nt)
#pragma unroll
            for (int r = 0; r < 4; ++r) {
                float p = __builtin_amdgcn_exp2f(sc[nt][r] - m_run);
                sc[nt][r] = p;
                rs += p;
            }
        rs += __shfl_xor(rs, 16);
        rs += __shfl_xor(rs, 32);
        l_run += rs;
        // P^T (C-layout) -> P A-layout via wave-private packed LDS
#pragma unroll
        for (int nt = 0; nt < 4; ++nt) {
            u32x2 w;
            w[0] = pkbf(sc[nt][0], sc[nt][1]);
            w[1] = pkbf(sc[nt][2], sc[nt][3]);
            *(u32x2*)(&Pw[c * 36 + nt * 8 + g * 2]) = w;
        }
        __builtin_amdgcn_s_setprio(1);
#pragma unroll
        for (int kc = 0; kc < 2; ++kc) {
            s16x8 pf = *(const s16x8*)(&Pw[c * 36 + kc * 16 + g * 4]);
            const int xv = kc ? x1 : x0;
#pragma unroll
            for (int dt = 0; dt < 4; ++dt) {
                s16x8 vf = *(const s16x8*)(&Vc[(dt * 16 + c) * 64 + xv]);
                o[dt] = __builtin_amdgcn_mfma_f32_16x16x32_bf16(pf, vf, o[dt], 0, 0, 0);
            }
        }
        __builtin_amdgcn_s_setprio(0);
    }
    // epilogue: normalize rows, write [B][S][E] bf16
    float linv = 1.0f / l_run;
    float lv[4];
#pragma unroll
    for (int r = 0; r < 4; ++r) lv[r] = __shfl(linv, g * 4 + r, 16);
#pragma unroll
    for (int r = 0; r < 4; ++r) {
        int sr = qt * 64 + wr * 16 + g * 4 + r;
        size_t base = ((size_t)b * SEQ + sr) * EMBED + h * HD;
#pragma unroll
        for (int dt = 0; dt < 4; ++dt)
            Ob[base + dt * 16 + c] = f2bf(o[dt][r] * lv[r]);
    }
}

extern "C" void kernel_launch(void* const* d_in, const int* in_sizes, int n_in,
                              void* d_out, int out_size, void* d_ws, size_t ws_size,
                              hipStream_t stream)
{
    (void)in_sizes; (void)n_in; (void)out_size; (void)ws_size;
    const float* Xq = (const float*)d_in[0];
    const float* Xk = (const float*)d_in[1];
    const float* Xv = (const float*)d_in[2];
    // d_in[3] = attn_mask: tril(ones) -> causal handled analytically
    const float* Wq = (const float*)d_in[4];
    const float* bq = (const float*)d_in[5];
    const float* Wk = (const float*)d_in[6];
    const float* bk = (const float*)d_in[7];
    const float* Wv = (const float*)d_in[8];
    const float* bv = (const float*)d_in[9];
    const float* Wo = (const float*)d_in[10];
    const float* bo = (const float*)d_in[11];
    float* Out = (float*)d_out;

    unsigned short* ws = (unsigned short*)d_ws;
    unsigned short* wqb = ws;                    // 4 x 1M elts (weights bf16)
    unsigned short* wkb = wqb + 1048576;
    unsigned short* wvb = wkb + 1048576;
    unsigned short* wob = wvb + 1048576;
    unsigned short* xqb = wob + 1048576;         // 3 x 8M elts (X bf16)
    unsigned short* xkb = xqb + 8388608;
    unsigned short* xvb = xkb + 8388608;
    unsigned short* Qb  = xvb + 8388608;         // [B][H][S][D] bf16
    unsigned short* Kb  = Qb + 8388608;          // [B][H][S][D] bf16
    unsigned short* Vb  = Kb + 8388608;          // [B][H][D][S] bf16 (V^T)
    unsigned short* Ax  = xqb;                   // attn out bf16 [B][S][E]
                                                 // (aliases xqb: dead after gemm_qkv)

    CvtArgs ca;
    ca.s[0] = Wq; ca.s[1] = Wk; ca.s[2] = Wv; ca.s[3] = Wo;
    ca.s[4] = Xq; ca.s[5] = Xk; ca.s[6] = Xv;
    ca.d[0] = wqb; ca.d[1] = wkb; ca.d[2] = wvb; ca.d[3] = wob;
    ca.d[4] = xqb; ca.d[5] = xkb; ca.d[6] = xvb;
    ca.n4[0] = ca.n4[1] = ca.n4[2] = ca.n4[3] = 262144;    // 1024*1024/4
    ca.n4[4] = ca.n4[5] = ca.n4[6] = 2097152;              // 8192*1024/4
    cvt_all<<<dim3(2048, 7), 256, 0, stream>>>(ca);

    ProjArgs pa;
    pa.X[0] = xqb; pa.X[1] = xkb; pa.X[2] = xvb;
    pa.W[0] = wqb; pa.W[1] = wkb; pa.W[2] = wvb;
    pa.Bz[0] = bq; pa.Bz[1] = bk; pa.Bz[2] = bv;
    pa.Oz[0] = Qb; pa.Oz[1] = Kb; pa.Oz[2] = Vb;
    gemm_qkv<<<dim3(32, 8, 3), 256, 0, stream>>>(pa);

    attn_fwd<<<dim3(NH, 4, 16), 512, 0, stream>>>(Qb, Kb, Vb, Ax);

    gemm_out<<<dim3(64, 8), 256, 0, stream>>>(Ax, wob, bo, Out);
}

// Round 7
// 316.646 us; speedup vs baseline: 1.1679x; 1.1679x over previous
//
#include <hip/hip_runtime.h>
#include <math.h>

// MHA forward: B=4, S=2048, E=1024, H=16, D=64. bf16 MFMA path.
// Round 11: surgical revert of round-10's gemm_qkv pairing (VGPR 112->144
// crossed the 128 boundary -> 3 waves/SIMD, occupancy collapse, 75->131us).
// gemm_qkv is back to the round-9 structure (one 128^2 M-tile per block,
// grid 64x8x3) with __launch_bounds__(256,4) pinned as a VGPR<=128 guard.
// attn_fwd keeps round-10's T5 setprio (measured ~4us gain via total-delta).

#define EMBED 1024
#define SEQ   2048
#define NH    16
#define HD    64
#define QSCALE 0.18033688011112042f   // 0.125 * log2(e), folded into Q proj

typedef __attribute__((ext_vector_type(4))) float f32x4;
typedef __attribute__((ext_vector_type(8))) short s16x8;
typedef __attribute__((ext_vector_type(4))) short s16x4;
typedef __attribute__((ext_vector_type(4))) unsigned int u32x4;
typedef __attribute__((ext_vector_type(2))) unsigned int u32x2;

#define GLDS16(gp, lp) __builtin_amdgcn_global_load_lds( \
    (const __attribute__((address_space(1))) void*)(gp), \
    (__attribute__((address_space(3))) void*)(lp), 16, 0, 0)

__device__ __forceinline__ unsigned short f2bf(float f) {   // RNE
    unsigned int u = __builtin_bit_cast(unsigned int, f);
    u += 0x7fffu + ((u >> 16) & 1u);
    return (unsigned short)(u >> 16);
}
// pack two fp32 -> bf16x2 dword by truncation (1 v_perm_b32)
__device__ __forceinline__ unsigned int pkbf(float lo, float hi) {
    return __builtin_amdgcn_perm(__builtin_bit_cast(unsigned int, hi),
                                 __builtin_bit_cast(unsigned int, lo),
                                 0x07060302u);
}

// ---------- fp32 -> bf16 (RNE): 4 weight tensors + 3 activation tensors ----
struct CvtArgs { const float* s[7]; unsigned short* d[7]; int n4[7]; };
__global__ void cvt_all(CvtArgs ca)
{
    const int t = blockIdx.y;
    const float* in = ca.s[t];
    unsigned short* out = ca.d[t];
    const int n4 = ca.n4[t];
    const int stride = gridDim.x * 256;
    for (int i = blockIdx.x * 256 + threadIdx.x; i < n4; i += stride) {
        f32x4 v = *(const f32x4*)(in + (size_t)i * 4);
        s16x4 p;
        p[0] = (short)f2bf(v[0]); p[1] = (short)f2bf(v[1]);
        p[2] = (short)f2bf(v[2]); p[3] = (short)f2bf(v[3]);
        *(s16x4*)(out + (size_t)i * 4) = p;
    }
}

// ---------------- QKV projection (z = 0:Q, 1:K, 2:V), pure bf16 ------------
struct ProjArgs {
    const unsigned short* X[3];
    const unsigned short* W[3];
    const float* Bz[3];
    unsigned short* Oz[3];
};
__global__ void __launch_bounds__(256, 4)
gemm_qkv(ProjArgs pa)
{
    __shared__ unsigned short Ab[128 * 64];    // bf16 X tile (16 KB), swizzled
    __shared__ unsigned short Bb[128 * 64];    // bf16 W tile (16 KB), swizzled
    const int z = blockIdx.z;
    const unsigned short* Xb = pa.X[z];
    const unsigned short* Wb = pa.W[z];
    const float* bias = pa.Bz[z];
    unsigned short* Out = pa.Oz[z];
    const float scale = (z == 0) ? QSCALE : 1.0f;
    const int tid = threadIdx.x, lane = tid & 63, wv = tid >> 6;
    const int g = lane >> 4, c = lane & 15;
    const int wx = wv & 1, wy = wv >> 1;
    const int bm0 = blockIdx.x * 128, bn0 = blockIdx.y * 128;

    f32x4 acc[4][4];
#pragma unroll
    for (int i = 0; i < 4; ++i)
#pragma unroll
        for (int n = 0; n < 4; ++n) acc[i][n] = f32x4{0.f, 0.f, 0.f, 0.f};

    for (int k0 = 0; k0 < EMBED; k0 += 64) {
        __syncthreads();
#pragma unroll
        for (int cc = 0; cc < 4; ++cc) {       // A bf16: 8 chunks/row, swz ^(row&7)
            int li = cc * 256 + tid;
            int row = li >> 3, ch = (li & 7) ^ (row & 7);
            GLDS16(Xb + (size_t)(bm0 + row) * EMBED + k0 + ch * 8,
                   Ab + cc * 2048 + wv * 512);
        }
#pragma unroll
        for (int cc = 0; cc < 4; ++cc) {       // B bf16: 8 chunks/row, swz ^(row&7)
            int li = cc * 256 + tid;
            int row = li >> 3, ch = (li & 7) ^ (row & 7);
            GLDS16(Wb + (size_t)(bn0 + row) * EMBED + k0 + ch * 8,
                   Bb + cc * 2048 + wv * 512);
        }
        __syncthreads();
#pragma unroll
        for (int ks = 0; ks < 2; ++ks) {
            const int ib = ((ks * 4 + g) ^ (c & 7)) * 8;
            s16x8 af[4], bfr[4];
#pragma unroll
            for (int i = 0; i < 4; ++i)
                af[i] = *(const s16x8*)(&Ab[(wy * 64 + i * 16 + c) * 64 + ib]);
#pragma unroll
            for (int n = 0; n < 4; ++n)
                bfr[n] = *(const s16x8*)(&Bb[(wx * 64 + n * 16 + c) * 64 + ib]);
#pragma unroll
            for (int i = 0; i < 4; ++i)
#pragma unroll
                for (int n = 0; n < 4; ++n)
                    acc[i][n] = __builtin_amdgcn_mfma_f32_16x16x32_bf16(af[i], bfr[n], acc[i][n], 0, 0, 0);
        }
    }
    if (z < 2) {        // Q/K -> [B][H][S][D]
#pragma unroll
        for (int i = 0; i < 4; ++i) {
            int m0 = bm0 + wy * 64 + i * 16 + g * 4;
            int bb = m0 >> 11, s0 = m0 & 2047;
#pragma unroll
            for (int n = 0; n < 4; ++n) {
                int ncol = bn0 + wx * 64 + n * 16 + c;
                float bv = bias[ncol];
                int hh = ncol >> 6, dd = ncol & 63;
                size_t base = (((size_t)bb * NH + hh) * SEQ + s0) * HD + dd;
#pragma unroll
                for (int r = 0; r < 4; ++r)
                    Out[base + (size_t)r * HD] = f2bf((acc[i][n][r] + bv) * scale);
            }
        }
    } else {            // V -> V^T [B][H][D][S], 8B stores
#pragma unroll
        for (int i = 0; i < 4; ++i) {
            int m0 = bm0 + wy * 64 + i * 16 + g * 4;
            int bb = m0 >> 11, s0 = m0 & 2047;
#pragma unroll
            for (int n = 0; n < 4; ++n) {
                int ncol = bn0 + wx * 64 + n * 16 + c;
                float bv = bias[ncol];
                int hh = ncol >> 6, dd = ncol & 63;
                s16x4 pk;
#pragma unroll
                for (int r = 0; r < 4; ++r) pk[r] = (short)f2bf(acc[i][n][r] + bv);
                *(s16x4*)(&Out[(((size_t)bb * NH + hh) * HD + dd) * SEQ + s0]) = pk;
            }
        }
    }
}

// ---------------- output projection -----------------------------------------
__global__ void __launch_bounds__(256, 4)
gemm_out(const unsigned short* __restrict__ Xb, const unsigned short* __restrict__ Wb,
         const float* __restrict__ bias, float* __restrict__ Out)
{
    __shared__ unsigned short Ab[128 * 64];
    __shared__ unsigned short Bb[128 * 64];
    const int tid = threadIdx.x;
    const int lane = tid & 63, wv = tid >> 6;
    const int g = lane >> 4, c = lane & 15;
    const int wx = wv & 1, wy = wv >> 1;
    const int bm0 = blockIdx.x * 128, bn0 = blockIdx.y * 128;

    f32x4 acc[4][4];
#pragma unroll
    for (int i = 0; i < 4; ++i)
#pragma unroll
        for (int n = 0; n < 4; ++n) acc[i][n] = f32x4{0.f, 0.f, 0.f, 0.f};

    for (int k0 = 0; k0 < EMBED; k0 += 64) {
        __syncthreads();
#pragma unroll
        for (int cc = 0; cc < 4; ++cc) {
            int li = cc * 256 + tid;
            int row = li >> 3, ch = (li & 7) ^ (row & 7);
            GLDS16(Xb + (size_t)(bm0 + row) * EMBED + k0 + ch * 8,
                   Ab + cc * 2048 + wv * 512);
        }
#pragma unroll
        for (int cc = 0; cc < 4; ++cc) {
            int li = cc * 256 + tid;
            int row = li >> 3, ch = (li & 7) ^ (row & 7);
            GLDS16(Wb + (size_t)(bn0 + row) * EMBED + k0 + ch * 8,
                   Bb + cc * 2048 + wv * 512);
        }
        __syncthreads();
#pragma unroll
        for (int ks = 0; ks < 2; ++ks) {
            const int ib = ((ks * 4 + g) ^ (c & 7)) * 8;
            s16x8 af[4], bfr[4];
#pragma unroll
            for (int i = 0; i < 4; ++i)
                af[i] = *(const s16x8*)(&Ab[(wy * 64 + i * 16 + c) * 64 + ib]);
#pragma unroll
            for (int n = 0; n < 4; ++n)
                bfr[n] = *(const s16x8*)(&Bb[(wx * 64 + n * 16 + c) * 64 + ib]);
#pragma unroll
            for (int i = 0; i < 4; ++i)
#pragma unroll
                for (int n = 0; n < 4; ++n)
                    acc[i][n] = __builtin_amdgcn_mfma_f32_16x16x32_bf16(af[i], bfr[n], acc[i][n], 0, 0, 0);
        }
    }
#pragma unroll
    for (int i = 0; i < 4; ++i) {
#pragma unroll
        for (int n = 0; n < 4; ++n) {
            int ncol = bn0 + wx * 64 + n * 16 + c;
            float bv = bias[ncol];
#pragma unroll
            for (int r = 0; r < 4; ++r) {
                int m = bm0 + wy * 64 + i * 16 + g * 4 + r;
                Out[(size_t)m * EMBED + ncol] = acc[i][n][r] + bv;
            }
        }
    }
}

// ---------------- causal flash attention (8-wave, unpaired stripes) ---------
// grid (NH, B, 16); block = 8 waves (512 thr). One stripe per block: waves
// 0-3 own q-tile 2jj, waves 4-7 own q-tile 2jj+1, sharing one double-buffered
// K/V LDS pipeline. jj = 15 - blockIdx.z puts the 34-iter stripes first in
// dispatch order (global LPT); LDS 51200 -> 3 blocks/CU co-resident.
// defer-max: O-rescale skipped unless tile max exceeds m_run+8 (exp2 dom).
// setprio(1) around QK^T and PV MFMA clusters (T5).
__global__ void __launch_bounds__(512, 4)
attn_fwd(const unsigned short* __restrict__ Qb, const unsigned short* __restrict__ Kb,
         const unsigned short* __restrict__ Vg, unsigned short* __restrict__ Ob)
{
    __shared__ unsigned short Kt[2][64 * 64];  // K tile [s][d], swizzled (16 KB)
    __shared__ unsigned short Vt[2][64 * 64];  // V^T tile [d][s], swizzled (16 KB)
    __shared__ unsigned int   Pb[8][16 * 36];  // per-wave P, dwords, stride 36
    const int tid = threadIdx.x, lane = tid & 63, wv = tid >> 6;
    const int g = lane >> 4, c = lane & 15;
    const int wq = wv >> 2, wr = wv & 3;       // q-tile select / row-group
    const int h = blockIdx.x, b = blockIdx.y;
    const int jj = 15 - blockIdx.z;            // stripe (LPT: big first)
    const size_t bh = (size_t)b * NH + h;
    const unsigned short* K0 = Kb + bh * SEQ * HD;
    const unsigned short* V0 = Vg + bh * HD * SEQ;
    unsigned int* Pw = &Pb[wv][0];
    const int x0 = (g ^ (c & 7)) * 8;          // swizzled chunk offsets (LDS)
    const int x1 = ((4 + g) ^ (c & 7)) * 8;
    // staging: 512 threads cover 64 rows x 8 chunks (one GLDS16 each)
    const int srow = tid >> 3, sch = (tid & 7) ^ (srow & 7);
    const int kr = srow * HD + sch * 8;
    const int vr = srow * SEQ + sch * 8;

    const int qt = 2 * jj + wq;          // this wave's q-tile
    const int kmax = 2 * jj + 1;         // block-wide last k-tile
    const unsigned short* Qp = Qb + (bh * SEQ + qt * 64 + wr * 16) * HD;
    s16x8 qf0 = *(const s16x8*)(Qp + c * HD + g * 8);
    s16x8 qf1 = *(const s16x8*)(Qp + c * HD + 32 + g * 8);
    f32x4 o[4];
#pragma unroll
    for (int dt = 0; dt < 4; ++dt) o[dt] = f32x4{0.f, 0.f, 0.f, 0.f};
    float m_run = -INFINITY, l_run = 0.f;

    {   // prologue: stage K/V(0) into buffer 0
        GLDS16(K0 + kr, &Kt[0][0] + wv * 512);
        GLDS16(V0 + vr, &Vt[0][0] + wv * 512);
    }

    for (int kt = 0; kt <= kmax; ++kt) {
        __syncthreads();           // publishes buffer kt&1 (drains GLDS)
        const int cur = kt & 1;
        if (kt < kmax) {           // prefetch kt+1 into the other buffer
            GLDS16(K0 + (size_t)(kt + 1) * 64 * HD + kr, &Kt[cur ^ 1][0] + wv * 512);
            GLDS16(V0 + (kt + 1) * 64 + vr, &Vt[cur ^ 1][0] + wv * 512);
        }
        if (kt > qt) continue;     // wave-uniform: lower q-tile idles last iter
        const unsigned short* Kc = &Kt[cur][0];
        const unsigned short* Vc = &Vt[cur][0];

        const int ntmax = (kt == qt) ? wr : 3;   // skip fully-masked k-subtiles
        f32x4 sc[4];
        __builtin_amdgcn_s_setprio(1);
#pragma unroll
        for (int nt = 0; nt < 4; ++nt) {
            if (nt <= ntmax) {
                f32x4 a = f32x4{0.f, 0.f, 0.f, 0.f};
                s16x8 kf0 = *(const s16x8*)(&Kc[(nt * 16 + c) * 64 + x0]);
                s16x8 kf1 = *(const s16x8*)(&Kc[(nt * 16 + c) * 64 + x1]);
                a = __builtin_amdgcn_mfma_f32_16x16x32_bf16(kf0, qf0, a, 0, 0, 0);
                a = __builtin_amdgcn_mfma_f32_16x16x32_bf16(kf1, qf1, a, 0, 0, 0);
                sc[nt] = a;
            } else {
                sc[nt] = f32x4{-INFINITY, -INFINITY, -INFINITY, -INFINITY};
            }
        }
        __builtin_amdgcn_s_setprio(0);
        if (kt == qt) {   // diagonal tile: mask k > q
#pragma unroll
            for (int nt = 0; nt < 4; ++nt)
#pragma unroll
                for (int r = 0; r < 4; ++r)
                    if (nt * 16 + g * 4 + r > wr * 16 + c) sc[nt][r] = -INFINITY;
        }
        // online softmax: lane owns q-column c; k spread over regs+g
        float mloc = -INFINITY;
#pragma unroll
        for (int nt = 0; nt < 4; ++nt)
            mloc = fmaxf(mloc, fmaxf(fmaxf(sc[nt][0], sc[nt][1]),
                                     fmaxf(sc[nt][2], sc[nt][3])));
        mloc = fmaxf(mloc, __shfl_xor(mloc, 16));
        mloc = fmaxf(mloc, __shfl_xor(mloc, 32));
        // defer-max (T13): rescale only when growth exceeds 8 (exp2 domain);
        // P bounded by 2^8 = 256, safe in bf16 pack + fp32 accum.
        if (__any(mloc > m_run + 8.0f)) {
            float mnew = fmaxf(m_run, mloc);
            float alpha = __builtin_amdgcn_exp2f(m_run - mnew);
            m_run = mnew;
            l_run *= alpha;
            float av[4];
#pragma unroll
            for (int r = 0; r < 4; ++r) av[r] = __shfl(alpha, g * 4 + r, 16);
#pragma unroll
            for (int dt = 0; dt < 4; ++dt)
#pragma unroll
                for (int r = 0; r < 4; ++r) o[dt][r] *= av[r];
        }
        float rs = 0.f;
#pragma unroll
        for (int nt = 0; nt < 4; ++nt)
#pragma unroll
            for (int r = 0; r < 4; ++r) {
                float p = __builtin_amdgcn_exp2f(sc[nt][r] - m_run);
                sc[nt][r] = p;
                rs += p;
            }
        rs += __shfl_xor(rs, 16);
        rs += __shfl_xor(rs, 32);
        l_run += rs;
        // P^T (C-layout) -> P A-layout via wave-private packed LDS
#pragma unroll
        for (int nt = 0; nt < 4; ++nt) {
            u32x2 w;
            w[0] = pkbf(sc[nt][0], sc[nt][1]);
            w[1] = pkbf(sc[nt][2], sc[nt][3]);
            *(u32x2*)(&Pw[c * 36 + nt * 8 + g * 2]) = w;
        }
        __builtin_amdgcn_s_setprio(1);
#pragma unroll
        for (int kc = 0; kc < 2; ++kc) {
            s16x8 pf = *(const s16x8*)(&Pw[c * 36 + kc * 16 + g * 4]);
            const int xv = kc ? x1 : x0;
#pragma unroll
            for (int dt = 0; dt < 4; ++dt) {
                s16x8 vf = *(const s16x8*)(&Vc[(dt * 16 + c) * 64 + xv]);
                o[dt] = __builtin_amdgcn_mfma_f32_16x16x32_bf16(pf, vf, o[dt], 0, 0, 0);
            }
        }
        __builtin_amdgcn_s_setprio(0);
    }
    // epilogue: normalize rows, write [B][S][E] bf16
    float linv = 1.0f / l_run;
    float lv[4];
#pragma unroll
    for (int r = 0; r < 4; ++r) lv[r] = __shfl(linv, g * 4 + r, 16);
#pragma unroll
    for (int r = 0; r < 4; ++r) {
        int sr = qt * 64 + wr * 16 + g * 4 + r;
        size_t base = ((size_t)b * SEQ + sr) * EMBED + h * HD;
#pragma unroll
        for (int dt = 0; dt < 4; ++dt)
            Ob[base + dt * 16 + c] = f2bf(o[dt][r] * lv[r]);
    }
}

extern "C" void kernel_launch(void* const* d_in, const int* in_sizes, int n_in,
                              void* d_out, int out_size, void* d_ws, size_t ws_size,
                              hipStream_t stream)
{
    (void)in_sizes; (void)n_in; (void)out_size; (void)ws_size;
    const float* Xq = (const float*)d_in[0];
    const float* Xk = (const float*)d_in[1];
    const float* Xv = (const float*)d_in[2];
    // d_in[3] = attn_mask: tril(ones) -> causal handled analytically
    const float* Wq = (const float*)d_in[4];
    const float* bq = (const float*)d_in[5];
    const float* Wk = (const float*)d_in[6];
    const float* bk = (const float*)d_in[7];
    const float* Wv = (const float*)d_in[8];
    const float* bv = (const float*)d_in[9];
    const float* Wo = (const float*)d_in[10];
    const float* bo = (const float*)d_in[11];
    float* Out = (float*)d_out;

    unsigned short* ws = (unsigned short*)d_ws;
    unsigned short* wqb = ws;                    // 4 x 1M elts (weights bf16)
    unsigned short* wkb = wqb + 1048576;
    unsigned short* wvb = wkb + 1048576;
    unsigned short* wob = wvb + 1048576;
    unsigned short* xqb = wob + 1048576;         // 3 x 8M elts (X bf16)
    unsigned short* xkb = xqb + 8388608;
    unsigned short* xvb = xkb + 8388608;
    unsigned short* Qb  = xvb + 8388608;         // [B][H][S][D] bf16
    unsigned short* Kb  = Qb + 8388608;          // [B][H][S][D] bf16
    unsigned short* Vb  = Kb + 8388608;          // [B][H][D][S] bf16 (V^T)
    unsigned short* Ax  = xqb;                   // attn out bf16 [B][S][E]
                                                 // (aliases xqb: dead after gemm_qkv)

    CvtArgs ca;
    ca.s[0] = Wq; ca.s[1] = Wk; ca.s[2] = Wv; ca.s[3] = Wo;
    ca.s[4] = Xq; ca.s[5] = Xk; ca.s[6] = Xv;
    ca.d[0] = wqb; ca.d[1] = wkb; ca.d[2] = wvb; ca.d[3] = wob;
    ca.d[4] = xqb; ca.d[5] = xkb; ca.d[6] = xvb;
    ca.n4[0] = ca.n4[1] = ca.n4[2] = ca.n4[3] = 262144;    // 1024*1024/4
    ca.n4[4] = ca.n4[5] = ca.n4[6] = 2097152;              // 8192*1024/4
    cvt_all<<<dim3(2048, 7), 256, 0, stream>>>(ca);

    ProjArgs pa;
    pa.X[0] = xqb; pa.X[1] = xkb; pa.X[2] = xvb;
    pa.W[0] = wqb; pa.W[1] = wkb; pa.W[2] = wvb;
    pa.Bz[0] = bq; pa.Bz[1] = bk; pa.Bz[2] = bv;
    pa.Oz[0] = Qb; pa.Oz[1] = Kb; pa.Oz[2] = Vb;
    gemm_qkv<<<dim3(64, 8, 3), 256, 0, stream>>>(pa);

    attn_fwd<<<dim3(NH, 4, 16), 512, 0, stream>>>(Qb, Kb, Vb, Ax);

    gemm_out<<<dim3(64, 8), 256, 0, stream>>>(Ax, wob, bo, Out);
}